// Round 4
// baseline (381.180 us; speedup 1.0000x reference)
//
#include <hip/hip_runtime.h>
#include <math.h>

#define B_    32
#define C_    256
#define HF    64
#define WF    64
#define M_    4096   // HF*WF
#define N_    128
#define IMGM1 1023.0f
#define TEMP_ 0.1f
#define EPS_  1e-12f
#define BM2   64     // m per block in k2
#define NMB   (M_ / BM2)   // 64 m-blocks

typedef __attribute__((ext_vector_type(8))) short short8;
typedef __attribute__((ext_vector_type(4))) float floatx4;

__device__ __forceinline__ unsigned short f2bf(float x) {  // RNE fp32->bf16
  unsigned int u = __float_as_uint(x);
  u += 0x7fffu + ((u >> 16) & 1u);
  return (unsigned short)(u >> 16);
}
__device__ __forceinline__ float bf2f(unsigned short h) {
  return __uint_as_float(((unsigned int)h) << 16);
}
__device__ __forceinline__ float wave_sum(float v) {
#pragma unroll
  for (int off = 32; off; off >>= 1) v += __shfl_down(v, off, 64);
  return v;
}
// async global->LDS DMA, 16B per lane; LDS dest = base + lane*16 (wave-uniform base)
__device__ __forceinline__ void gl2lds16(const void* g, void* l) {
  __builtin_amdgcn_global_load_lds((const __attribute__((address_space(1))) unsigned int*)g,
                                   (__attribute__((address_space(3))) unsigned int*)l, 16, 0, 0);
}
__device__ __forceinline__ float4 shflx4(float4 v, int m) {
  float4 r;
  r.x = __shfl_xor(v.x, m, 64);
  r.y = __shfl_xor(v.y, m, 64);
  r.z = __shfl_xor(v.z, m, 64);
  r.w = __shfl_xor(v.w, m, 64);
  return r;
}
// 4x4 transpose across 4 lanes (varying low-2 lane bits e); lane e's input = row e
// (cols c0..c3); output = column e (rows 0..3).
__device__ __forceinline__ float4 t4x4(float4 v, int e) {
  float4 p = shflx4(v, 1);
  float4 w = ((e & 1) == 0) ? make_float4(v.x, p.x, v.z, p.z)
                            : make_float4(p.y, v.y, p.w, v.w);
  float4 p2 = shflx4(w, 2);
  return ((e & 2) == 0) ? make_float4(w.x, w.y, p2.x, p2.y)
                        : make_float4(p2.z, p2.w, w.z, w.w);
}

__device__ __forceinline__ void src_geom(float kx, float ky, int& x0, int& y0,
                                         int& x1, int& y1, float& fx, float& fy) {
  const float x = kx / IMGM1 * (float)(WF - 1);
  const float y = ky / IMGM1 * (float)(HF - 1);
  x0 = (int)fminf(fmaxf(floorf(x), 0.f), 63.f);
  y0 = (int)fminf(fmaxf(floorf(y), 0.f), 63.f);
  x1 = min(x0 + 1, 63);
  y1 = min(y0 + 1, 63);
  fx = x - (float)x0;
  fy = y - (float)y0;
}

// ============ k1a: coalesced plane staging -> corner gather (bf16) + ssq atomics ============
__global__ __launch_bounds__(256) void k1a_stage(const float* __restrict__ fs,
                                                 const float* __restrict__ kps,
                                                 ushort* __restrict__ corner,
                                                 float* __restrict__ ssqg) {
  const int cg = blockIdx.x, b = blockIdx.y, t = threadIdx.x;
  const int c0 = cg * 2;
  __shared__ __align__(16) float plane[2 * M_];   // 32 KB
  __shared__ float4 ssq2[256];

  const float4* src = (const float4*)(fs + ((size_t)(b * C_ + c0)) * M_);
  float4* dst = (float4*)plane;
#pragma unroll
  for (int i = 0; i < 8; i++) dst[t + 256 * i] = src[t + 256 * i];
  __syncthreads();

  const int n = t & 127, p = t >> 7;
  const int c = c0 + p;
  const float kx = kps[((size_t)b * N_ + n) * 2 + 0];
  const float ky = kps[((size_t)b * N_ + n) * 2 + 1];
  int x0, y0, x1, y1; float fx, fy;
  src_geom(kx, ky, x0, y0, x1, y1, fx, fy);

  const float* pl = plane + p * M_;
  const float f00 = pl[y0 * WF + x0];
  const float f10 = pl[y1 * WF + x0];
  const float f01 = pl[y0 * WF + x1];
  const float f11 = pl[y1 * WF + x1];

  ushort4 cr;
  cr.x = f2bf(f00); cr.y = f2bf(f10); cr.z = f2bf(f01); cr.w = f2bf(f11);
  *(ushort4*)&corner[(((size_t)b * C_ + c) * N_ + n) * 4] = cr;

  ssq2[t] = make_float4(f00 * f00, f10 * f10, f01 * f01, f11 * f11);
  __syncthreads();
  if (t < 128) {
    const float4 a = ssq2[t], bq = ssq2[t + 128];
    float* g = ssqg + ((size_t)b * N_ + t) * 4;
    atomicAdd(g + 0, a.x + bq.x);
    atomicAdd(g + 1, a.y + bq.y);
    atomicAdd(g + 2, a.z + bq.z);
    atomicAdd(g + 3, a.w + bq.w);
  }
}

// ============ k1b: normalize + bilinear blend -> q (bf16, [b][n][c]) ============
__global__ __launch_bounds__(256) void k1b_combine(const ushort* __restrict__ corner,
                                                   const float* __restrict__ ssqg,
                                                   const float* __restrict__ kps,
                                                   ushort* __restrict__ qbf) {
  const int n = blockIdx.x, b = blockIdx.y, c = threadIdx.x;
  const float kx = kps[((size_t)b * N_ + n) * 2 + 0];
  const float ky = kps[((size_t)b * N_ + n) * 2 + 1];
  int x0, y0, x1, y1; float fx, fy;
  src_geom(kx, ky, x0, y0, x1, y1, fx, fy);
  const float wa = (1.f - fx) * (1.f - fy), wb = (1.f - fx) * fy;
  const float wc = fx * (1.f - fy), wd = fx * fy;

  const float4 sq = *(const float4*)&ssqg[((size_t)b * N_ + n) * 4];
  const float r0 = 1.f / fmaxf(sqrtf(sq.x), EPS_);
  const float r1 = 1.f / fmaxf(sqrtf(sq.y), EPS_);
  const float r2 = 1.f / fmaxf(sqrtf(sq.z), EPS_);
  const float r3 = 1.f / fmaxf(sqrtf(sq.w), EPS_);

  const ushort4 cr = *(const ushort4*)&corner[(((size_t)b * C_ + c) * N_ + n) * 4];
  const float qv = wa * bf2f(cr.x) * r0 + wb * bf2f(cr.y) * r1 +
                   wc * bf2f(cr.z) * r2 + wd * bf2f(cr.w) * r3;
  qbf[((size_t)b * N_ + n) * C_ + c] = f2bf(qv);
}

// ============ k2: barrier-free-K-loop MFMA logits ============
// grid (NMB, B_), block 256 = 4 waves; each wave owns 128n x 16m strip.
// A (q) staged once in LDS via swizzled global_load_lds; B (trg) transposed
// in-register via shfl_xor butterflies; trg column norms from fp32 loads.
__global__ __launch_bounds__(256) void k2_mfma(const float* __restrict__ trg,
                                               const ushort* __restrict__ qbf,
                                               const float* __restrict__ kps_trg,
                                               const int* __restrict__ mask,
                                               float2* __restrict__ part,
                                               float* __restrict__ tacc) {
  const int t = threadIdx.x;
  const int mb = blockIdx.x, b = blockIdx.y;
  const int wave = t >> 6, lane = t & 63;
  const int lg = lane >> 4;              // g: 0..3 (k-group)
  const int q4 = (lane >> 2) & 3;        // q: 0..3 (m quad)
  const int e  = lane & 3;               // e: 0..3
  const int ln = lane & 15;              // m within strip = q4*4+e

  __shared__ __align__(16) ushort qlds[N_ * C_];   // 64 KB, chunk-swizzled
  __shared__ float2 lred[128][4];                  // per-row (max,sum) per wave
  __shared__ __align__(16) int   tidx[128][4];
  __shared__ __align__(16) float tw[128][4];

  // ---- stage q into LDS (chunk-XOR swizzle folded into global address) ----
  const char* qb = (const char*)(qbf + (size_t)b * N_ * C_);
#pragma unroll
  for (int it = 0; it < 16; it++) {
    const int flat = it * 256 + t;
    const int r = flat >> 5, cs = flat & 31;            // row (512B), 16B chunk
    gl2lds16(qb + r * 512 + ((cs ^ (r & 7)) << 4),
             (char*)qlds + (it * 256 + wave * 64) * 16);
  }
  if (t < 128) {
    const float kx = kps_trg[((size_t)b * N_ + t) * 2 + 0];
    const float ky = kps_trg[((size_t)b * N_ + t) * 2 + 1];
    const float gx = kx * (1.f / 16.f), gy = ky * (1.f / 16.f);
    const int x0 = (int)fminf(fmaxf(floorf(gx), 0.f), 63.f);
    const int y0 = (int)fminf(fmaxf(floorf(gy), 0.f), 63.f);
    const int x1 = min(x0 + 1, 63), y1 = min(y0 + 1, 63);
    const float x0f = (float)x0, x1f = (float)x1, y0f = (float)y0, y1f = (float)y1;
    const float mk = (mask[(size_t)b * N_ + t] != 0) ? 1.f : 0.f;
    tidx[t][0] = y0 * WF + x0; tw[t][0] = (x1f - gx) * (y1f - gy) * mk;
    tidx[t][1] = y1 * WF + x0; tw[t][1] = (x1f - gx) * (gy - y0f) * mk;
    tidx[t][2] = y0 * WF + x1; tw[t][2] = (gx - x0f) * (y1f - gy) * mk;
    tidx[t][3] = y1 * WF + x1; tw[t][3] = (gx - x0f) * (gy - y0f) * mk;
  }
  __syncthreads();   // only barrier before the K-loop

  floatx4 acc[8];
#pragma unroll
  for (int i = 0; i < 8; i++) acc[i] = (floatx4)0.f;
  float4 ssq4 = make_float4(0.f, 0.f, 0.f, 0.f);

  // per-lane trg pointer: row g*8+e, col strip + q*4
  const float* pl = trg + (size_t)b * C_ * M_ + (size_t)(lg * 8 + e) * M_ +
                    mb * BM2 + wave * 16 + q4 * 4;

  float4 L0 = *(const float4*)pl;
  float4 L1 = *(const float4*)(pl + 4 * M_);
#pragma unroll
  for (int s = 0; s < 8; s++) {
    float4 N0 = L0, N1 = L1;
    if (s < 7) {
      N0 = *(const float4*)(pl + (size_t)(s + 1) * 32 * M_);
      N1 = *(const float4*)(pl + (size_t)((s + 1) * 32 + 4) * M_);
    }
    ssq4.x += L0.x * L0.x + L1.x * L1.x;
    ssq4.y += L0.y * L0.y + L1.y * L1.y;
    ssq4.z += L0.z * L0.z + L1.z * L1.z;
    ssq4.w += L0.w * L0.w + L1.w * L1.w;

    const float4 T0 = t4x4(L0, e);   // j=0..3: rows lg*8+0..3, col = strip+ln
    const float4 T1 = t4x4(L1, e);   // j=4..7
    short8 bfr;
    bfr[0] = (short)f2bf(T0.x); bfr[1] = (short)f2bf(T0.y);
    bfr[2] = (short)f2bf(T0.z); bfr[3] = (short)f2bf(T0.w);
    bfr[4] = (short)f2bf(T1.x); bfr[5] = (short)f2bf(T1.y);
    bfr[6] = (short)f2bf(T1.z); bfr[7] = (short)f2bf(T1.w);

#pragma unroll
    for (int i = 0; i < 8; i++) {
      const int row = i * 16 + ln;
      const int ch = (s * 4 + lg) ^ (row & 7);
      const short8 af = *(const short8*)&qlds[row * 256 + (ch << 3)];
      acc[i] = __builtin_amdgcn_mfma_f32_16x16x32_bf16(af, bfr, acc[i], 0, 0, 0);
    }
    L0 = N0; L1 = N1;
  }

  // ---- column norms: butterfly over e (1,2) and g (16,32); all lanes get totals of cols q4*4+0..3
#pragma unroll
  for (int m = 0; m < 4; m++) {
    const int msk = (m < 2) ? (1 << m) : (16 << (m - 2));
    const float4 o = shflx4(ssq4, msk);
    ssq4.x += o.x; ssq4.y += o.y; ssq4.z += o.z; ssq4.w += o.w;
  }
  const float tt = (e == 0) ? ssq4.x : (e == 1) ? ssq4.y : (e == 2) ? ssq4.z : ssq4.w;
  const float scl = 1.f / (fmaxf(sqrtf(tt), EPS_) * TEMP_);
#pragma unroll
  for (int i = 0; i < 8; i++) acc[i] *= scl;

  // ---- per-row (max,sumexp) over this wave's 16 m + target-logit extraction ----
  const int mglob = mb * BM2 + wave * 16 + ln;
#pragma unroll
  for (int i = 0; i < 8; i++) {
#pragma unroll
    for (int r = 0; r < 4; r++) {
      const float val = acc[i][r];
      float mx = val;
#pragma unroll
      for (int msk = 1; msk < 16; msk <<= 1) mx = fmaxf(mx, __shfl_xor(mx, msk, 64));
      float sm = __expf(val - mx);
#pragma unroll
      for (int msk = 1; msk < 16; msk <<= 1) sm += __shfl_xor(sm, msk, 64);
      const int nrow = i * 16 + lg * 4 + r;
      if (ln == 0) lred[nrow][wave] = make_float2(mx, sm);

      const int4  id4 = *(const int4*)&tidx[nrow][0];
      const float4 w4 = *(const float4*)&tw[nrow][0];
      if (id4.x == mglob && w4.x != 0.f) atomicAdd(&tacc[(size_t)b * N_ + nrow], w4.x * val);
      if (id4.y == mglob && w4.y != 0.f) atomicAdd(&tacc[(size_t)b * N_ + nrow], w4.y * val);
      if (id4.z == mglob && w4.z != 0.f) atomicAdd(&tacc[(size_t)b * N_ + nrow], w4.z * val);
      if (id4.w == mglob && w4.w != 0.f) atomicAdd(&tacc[(size_t)b * N_ + nrow], w4.w * val);
    }
  }
  __syncthreads();
  if (t < 128) {
    const float2 a = lred[t][0], bq = lred[t][1], c = lred[t][2], d = lred[t][3];
    float M = fmaxf(fmaxf(a.x, bq.x), fmaxf(c.x, d.x));
    float S = a.y * __expf(a.x - M) + bq.y * __expf(bq.x - M) +
              c.y * __expf(c.x - M) + d.y * __expf(d.x - M);
    part[((size_t)b * N_ + t) * NMB + mb] = make_float2(M, S);
  }
}

// ============ k4: per-(b,n) loss combine + masked-sum atomics ============
__global__ __launch_bounds__(128) void k4_comb(const float2* __restrict__ part,
                                               const float* __restrict__ tacc,
                                               const float* __restrict__ kps_trg,
                                               const int* __restrict__ mask,
                                               float* __restrict__ gs) {
  const int b = blockIdx.x, t = threadIdx.x;  // t = n
  const float2* p = part + ((size_t)b * N_ + t) * NMB;
  float M = -INFINITY;
#pragma unroll 8
  for (int c = 0; c < NMB; c++) M = fmaxf(M, p[c].x);
  float S = 0.f;
#pragma unroll 8
  for (int c = 0; c < NMB; c++) S += p[c].y * __expf(p[c].x - M);
  const float lse = M + logf(S);

  const float kx = kps_trg[((size_t)b * N_ + t) * 2 + 0];
  const float ky = kps_trg[((size_t)b * N_ + t) * 2 + 1];
  const float gx = kx * (1.f / 16.f), gy = ky * (1.f / 16.f);
  const int x0 = (int)fminf(fmaxf(floorf(gx), 0.f), 63.f);
  const int y0 = (int)fminf(fmaxf(floorf(gy), 0.f), 63.f);
  const int x1 = min(x0 + 1, 63), y1 = min(y0 + 1, 63);
  const float mk = (mask[(size_t)b * N_ + t] != 0) ? 1.f : 0.f;
  const float wsum = (float)(x1 - x0) * (float)(y1 - y0) * mk;

  float loss = wsum * lse - tacc[(size_t)b * N_ + t];
  float cnt = mk;
  loss = wave_sum(loss);
  cnt = wave_sum(cnt);
  __shared__ float sl[2], sc2[2];
  if ((t & 63) == 0) { sl[t >> 6] = loss; sc2[t >> 6] = cnt; }
  __syncthreads();
  if (t == 0) {
    atomicAdd(&gs[0], sl[0] + sl[1]);
    atomicAdd(&gs[1], sc2[0] + sc2[1]);
  }
}

__global__ void k5_final(const float* __restrict__ gs, float* __restrict__ out) {
  out[0] = gs[0] / fmaxf(gs[1], 1.f);
}

extern "C" void kernel_launch(void* const* d_in, const int* in_sizes, int n_in,
                              void* d_out, int out_size, void* d_ws, size_t ws_size,
                              hipStream_t stream) {
  const float* feats_src = (const float*)d_in[0];
  const float* feats_trg = (const float*)d_in[1];
  const float* kps_src   = (const float*)d_in[2];
  const float* kps_trg   = (const float*)d_in[3];
  const int*   kps_mask  = (const int*)d_in[4];
  float* out = (float*)d_out;

  // ws layout (bytes):
  //   0         ssqg   : B*N*4 floats   = 65536
  //   65536     tacc   : B*N floats     = 16384
  //   81920     gs     : 2 floats
  //   82432     corner : B*C*N*4 ushort = 8388608
  //   8471040   qbf    : B*N*C ushort   = 2097152
  //   10568192  part   : B*N*NMB float2 = 2097152   (ends ~12.7 MB; ws is 512 MiB)
  char* wsb = (char*)d_ws;
  float*  ssqg   = (float*)(wsb + 0);
  float*  tacc   = (float*)(wsb + 65536);
  float*  gs     = (float*)(wsb + 81920);
  ushort* corner = (ushort*)(wsb + 82432);
  ushort* qbf    = (ushort*)(wsb + 8471040);
  float2* part   = (float2*)(wsb + 10568192);

  hipMemsetAsync(wsb, 0, 81928, stream);  // zero ssqg + tacc + gs

  k1a_stage<<<dim3(C_ / 2, B_), 256, 0, stream>>>(feats_src, kps_src, corner, ssqg);
  k1b_combine<<<dim3(N_, B_), 256, 0, stream>>>(corner, ssqg, kps_src, qbf);
  k2_mfma<<<dim3(NMB, B_), 256, 0, stream>>>(feats_trg, qbf, kps_trg, kps_mask, part, tacc);
  k4_comb<<<dim3(B_), 128, 0, stream>>>(part, tacc, kps_trg, kps_mask, gs);
  k5_final<<<1, 1, 0, stream>>>(gs, out);
}